// Round 4
// baseline (4206.545 us; speedup 1.0000x reference)
//
#include <hip/hip_runtime.h>
#include <hip/hip_cooperative_groups.h>

namespace cg = cooperative_groups;

#define ALPHA_C 0.05f
#define BETA_C  0.95f
#define GAMMA_C 0.95f

constexpr int B = 16, T = 24, N = 512, F = 2, H = 64, E = 16;
constexpr int DA = 8;
constexpr int CC = F + H;    // 66
constexpr int TGN_OC = 32;
constexpr int GSZ = 256 * 512;   // grid threads

__device__ __forceinline__ float fast_rcp(float x) { return __builtin_amdgcn_rcpf(x); }
__device__ __forceinline__ float fast_tanh(float x) {
    // 1 - 2/(e^{2x}+1), rcp-based (error ~2^-22, fine vs threshold)
    return 1.0f - 2.0f * fast_rcp(__expf(2.0f * x) + 1.0f);
}
__device__ __forceinline__ float fast_sigmoid(float x) {
    return fast_rcp(1.0f + __expf(-x));
}

struct Prm {
    const float *sample, *A, *wq, *wk, *attn_bias, *attn_trans, *Wt, *btg;
    const float *Wa1, *ba1, *Wa2, *ba2, *Wsrc, *bsrc, *Wtgt, *btgt;
    const float *Wgz, *bgz, *Wgr, *bgr, *Wgc, *bgc, *Wsh, *bsh, *Wl, *bl, *Wm, *bm;
    float *hidden, *nvs, *nvt, *Mcomb, *K1, *K2, *comb, *comb2, *z, *P1, *P2;
    float *q, *kk, *th1, *th2, *tar32;
    float *out_gat, *out_gru, *out_fin, *out_attn;
};

union SM {
    struct { float m[64][68]; float h[64][68]; } bmm;                                  // 34.8 KB
    struct { float rows[32][516]; } a2;                                                // 66 KB
    struct { float d[32][194]; } gg;                                                   // 24.8 KB
    struct { float sn[32][16]; float tn[32][16]; float p[32][513]; float tot[32]; } adp; // 69.9 KB
    struct { float d[32][204]; } zr;                                                   // 26.1 KB
    struct { float m[64][65]; float h[64][2]; } tgn;                                   // 17.2 KB
};

// ---------------------------------------------------------------------------
// init: hidden=0, K1=gamma*A, K2=gamma*alpha*A + gamma^2*A^2
// A^2 tile: block (16x16 grid) -> 32x32 out tile, thread -> 2 outputs.
// ---------------------------------------------------------------------------
__device__ void phase_init(const Prm& p, SM& sm, int blk, int tid)
{
    int gt = blk * 512 + tid;
    for (int i = gt; i < B * N * H; i += GSZ) p.hidden[i] = 0.f;
    for (int i = gt; i < N * N; i += GSZ) p.K1[i] = GAMMA_C * p.A[i];

    int r0 = (blk >> 4) * 32, c0 = (blk & 15) * 32;
    for (int l = tid; l < 32 * 128; l += 512) {
        int row = l >> 7, k4 = (l & 127) << 2;
        *(float4*)&sm.a2.rows[row][k4] = *(const float4*)(p.A + (size_t)(r0 + row) * N + k4);
    }
    __syncthreads();
    int rr = tid >> 4, cc = tid & 15;
    float a0 = 0.f, a1 = 0.f;
    for (int k = 0; k < N; ++k) {
        float av = sm.a2.rows[rr][k];
        a0 += av * p.A[(size_t)k * N + c0 + cc];
        a1 += av * p.A[(size_t)k * N + c0 + 16 + cc];
    }
    size_t i0 = (size_t)(r0 + rr) * N + c0 + cc;
    p.K2[i0]      = GAMMA_C * ALPHA_C * p.A[i0]      + GAMMA_C * GAMMA_C * a0;
    p.K2[i0 + 16] = GAMMA_C * ALPHA_C * p.A[i0 + 16] + GAMMA_C * GAMMA_C * a1;
    __syncthreads();
}

// ---------------------------------------------------------------------------
// bmm unit: out_part[vhalf][b,w,c] = (vhalf==0 ? ALPHA*x : 0) + sum_{v half} M[v,w]*in[b,v,c]
// unit: w0=(u&7)*64, vhalf=(u>>3)&1, b=u>>4. thread: cg=tid&15 (4 cols), wg=tid>>4 (2 rows).
// ---------------------------------------------------------------------------
template<int GCOLS, bool INSUM, bool MPB>
__device__ void bmm_unit(SM& sm, float* __restrict__ out, const float* __restrict__ x,
                         const float* __restrict__ in, const float* __restrict__ M,
                         int unit, int tid)
{
    constexpr int Crow = 64 + GCOLS;
    const size_t pstr = (size_t)B * N * Crow;
    const int w0 = (unit & 7) * 64;
    const int vhalf = (unit >> 3) & 1;
    const int b = unit >> 4;
    const int cg = tid & 15;
    const int wg = tid >> 4;

    float acc[2][4] = {{0,0,0,0},{0,0,0,0}};
    float ag[2] = {0.f, 0.f};

    const float* Mb = M + (MPB ? (size_t)b * N * N : 0);
    const float* inb = in + (size_t)b * N * Crow;

    for (int vt = 0; vt < 4; ++vt) {
        const int v0 = vhalf * 256 + vt * 64;
#pragma unroll
        for (int it = 0; it < 2; ++it) {
            int l = it * 512 + tid;
            int row = l >> 4, c4 = (l & 15) << 2;
            *(float4*)&sm.bmm.m[row][c4] =
                *(const float4*)(Mb + (size_t)(v0 + row) * N + w0 + c4);
        }
        if (GCOLS == 2) {
            const float2* h0 = (const float2*)(inb + (size_t)v0 * Crow);
            const float2* h1 = (const float2*)(inb + pstr + (size_t)v0 * Crow);
            for (int l = tid; l < 64 * 33; l += 512) {
                int row = l / 33, k = (l - row * 33) * 2;
                float2 v = h0[l];
                if (INSUM) { float2 w = h1[l]; v.x += w.x; v.y += w.y; }
                *(float2*)&sm.bmm.h[row][k] = v;
            }
        } else {
            const float4* h0 = (const float4*)(inb + (size_t)v0 * Crow);
            const float4* h1 = (const float4*)(inb + pstr + (size_t)v0 * Crow);
#pragma unroll
            for (int it = 0; it < 2; ++it) {
                int l = it * 512 + tid;
                int row = l >> 4, k = (l & 15) << 2;
                float4 v = h0[l];
                if (INSUM) { float4 w = h1[l]; v.x += w.x; v.y += w.y; v.z += w.z; v.w += w.w; }
                *(float4*)&sm.bmm.h[row][k] = v;
            }
        }
        __syncthreads();
#pragma unroll 8
        for (int j = 0; j < 64; ++j) {
            float2 mv = *(const float2*)&sm.bmm.m[j][wg << 1];
            float4 hv = *(const float4*)&sm.bmm.h[j][cg << 2];
            acc[0][0] += mv.x * hv.x; acc[0][1] += mv.x * hv.y;
            acc[0][2] += mv.x * hv.z; acc[0][3] += mv.x * hv.w;
            acc[1][0] += mv.y * hv.x; acc[1][1] += mv.y * hv.y;
            acc[1][2] += mv.y * hv.z; acc[1][3] += mv.y * hv.w;
            if (GCOLS > 0 && cg < GCOLS) {
                float gv = sm.bmm.h[j][64 + cg];
                ag[0] += mv.x * gv; ag[1] += mv.y * gv;
            }
        }
        __syncthreads();
    }
    float* outp = out + (size_t)vhalf * pstr + (size_t)b * N * Crow;
    const float* xb = x + (size_t)b * N * Crow;
#pragma unroll
    for (int r = 0; r < 2; ++r) {
        const int w = w0 + (wg << 1) + r;
        const size_t base = (size_t)w * Crow + (cg << 2);
        if (GCOLS == 2) {
            float o0 = acc[r][0], o1 = acc[r][1], o2 = acc[r][2], o3 = acc[r][3];
            if (vhalf == 0) {
                o0 += ALPHA_C * xb[base];     o1 += ALPHA_C * xb[base + 1];
                o2 += ALPHA_C * xb[base + 2]; o3 += ALPHA_C * xb[base + 3];
            }
            float2 lo = {o0, o1}, hi = {o2, o3};
            *(float2*)(outp + base) = lo;
            *(float2*)(outp + base + 2) = hi;
            if (cg < GCOLS) {
                size_t gb = (size_t)w * Crow + 64 + cg;
                float v = ag[r];
                if (vhalf == 0) v += ALPHA_C * xb[gb];
                outp[gb] = v;
            }
        } else {
            float4 ov = {acc[r][0], acc[r][1], acc[r][2], acc[r][3]};
            if (vhalf == 0) {
                float4 xv = *(const float4*)(xb + base);
                ov.x += ALPHA_C * xv.x; ov.y += ALPHA_C * xv.y;
                ov.z += ALPHA_C * xv.z; ov.w += ALPHA_C * xv.w;
            }
            *(float4*)(outp + base) = ov;
        }
    }
}

// ---------------------------------------------------------------------------
// gsgt: 32 rows/block; stages [hidden | P1sum | P2sum]; 1 row/thread (e=tid&15).
// Also writes comb = [graph | hidden].
// ---------------------------------------------------------------------------
__device__ void phase_gsgt(const Prm& p, SM& sm, const float* graph, long gstride, int blk, int tid)
{
    const size_t psH = (size_t)B * N * H;
    const size_t nn0 = (size_t)blk * 32;
    const float4* h4  = (const float4*)(p.hidden + nn0 * H);
    const float4* p1a = (const float4*)(p.P1 + nn0 * H);
    const float4* p1b = (const float4*)(p.P1 + psH + nn0 * H);
    const float4* p2a = (const float4*)(p.P2 + nn0 * H);
    const float4* p2b = (const float4*)(p.P2 + psH + nn0 * H);
    {
        int l = tid;                       // 512 float4 units exactly
        int row = l >> 4, k = (l & 15) << 2;
        *(float4*)&sm.gg.d[row][k] = h4[l];
        float4 a = p1a[l], b2 = p1b[l];
        a.x += b2.x; a.y += b2.y; a.z += b2.z; a.w += b2.w;
        *(float4*)&sm.gg.d[row][64 + k] = a;
        float4 c = p2a[l], d2 = p2b[l];
        c.x += d2.x; c.y += d2.y; c.z += d2.z; c.w += d2.w;
        *(float4*)&sm.gg.d[row][128 + k] = c;
    }
    __syncthreads();
    int e = tid & 15, rg = tid >> 4;
    float gs = p.ba1[e], gt = p.ba2[e];
#pragma unroll 4
    for (int sk = 0; sk < 192; ++sk) {
        float v = sm.gg.d[rg][sk];
        gs += v * p.Wa1[(size_t)sk * E + e];
        gt += v * p.Wa2[(size_t)sk * E + e];
    }
    {
        size_t nn = nn0 + rg;
        int b = (int)(nn >> 9), n = (int)(nn & (N - 1));
        const float* g = graph + (size_t)b * gstride + (size_t)n * F;
        float g0 = g[0], g1 = g[1];
        float es = g0 * p.Wsrc[e] + g1 * p.Wsrc[E + e] + p.bsrc[e];
        float et = g0 * p.Wtgt[e] + g1 * p.Wtgt[E + e] + p.btgt[e];
        p.nvs[nn * E + e] = fast_tanh(2.0f * es * gs);
        p.nvt[nn * E + e] = fast_tanh(2.0f * et * gt);
    }
    for (int l = tid; l < 32 * CC; l += 512) {
        int row = l / CC, k = l - row * CC;
        size_t nn2 = nn0 + row;
        float v;
        if (k < F) {
            int b2 = (int)(nn2 >> 9), n2 = (int)(nn2 & (N - 1));
            v = graph[(size_t)b2 * gstride + (size_t)n2 * F + k];
        } else v = sm.gg.d[row][k - F];
        p.comb[nn2 * CC + k] = v;
    }
    __syncthreads();
}

// ---------------------------------------------------------------------------
// adp: block -> (b=blk>>4, n0=(blk&15)*32); thread = column m. Builds p in LDS,
// row-reduces, writes Mcomb = gamma*A + (beta/rowsum)*p.
// ---------------------------------------------------------------------------
__device__ void phase_adp(const Prm& p, SM& sm, int blk, int tid)
{
    int b = blk >> 4;
    int n0 = (blk & 15) * 32;
    const float* nvs_b = p.nvs + (size_t)b * N * E;
    const float* nvt_b = p.nvt + (size_t)b * N * E;
    if (tid < 128)      ((float4*)&sm.adp.sn[0][0])[tid]       = ((const float4*)(nvs_b + (size_t)n0 * E))[tid];
    else if (tid < 256) ((float4*)&sm.adp.tn[0][0])[tid - 128] = ((const float4*)(nvt_b + (size_t)n0 * E))[tid - 128];
    int m = tid;
    float smr[16], tmr[16];
    {
        const float4* s4 = (const float4*)(nvs_b + (size_t)m * E);
        const float4* t4 = (const float4*)(nvt_b + (size_t)m * E);
#pragma unroll
        for (int d = 0; d < 4; ++d) { *(float4*)&smr[4 * d] = s4[d]; *(float4*)&tmr[4 * d] = t4[d]; }
    }
    __syncthreads();
#pragma unroll 2
    for (int n = 0; n < 32; ++n) {
        float a1 = 0.f, a2 = 0.f;
#pragma unroll
        for (int d = 0; d < 16; ++d) {
            a1 += sm.adp.sn[n][d] * tmr[d];
            a2 += sm.adp.tn[n][d] * smr[d];
        }
        float pv = fmaxf(fast_tanh(2.0f * (a1 - a2)), 0.f);
        if (m == n0 + n) pv += 1.f;
        sm.adp.p[n][m] = pv;
    }
    __syncthreads();
    int wid = tid >> 6, lane = tid & 63;
#pragma unroll
    for (int rr = 0; rr < 4; ++rr) {
        int row = wid * 4 + rr;
        float s = 0.f;
#pragma unroll
        for (int k = 0; k < 8; ++k) s += sm.adp.p[row][lane + 64 * k];
        for (int o = 32; o > 0; o >>= 1) s += __shfl_down(s, o);
        if (lane == 0) sm.adp.tot[row] = BETA_C * fast_rcp(s);
    }
    __syncthreads();
    const float* Arow = p.A + (size_t)n0 * N;
    float* Mrow = p.Mcomb + ((size_t)b * N + n0) * N;
#pragma unroll 2
    for (int n = 0; n < 32; ++n) {
        float bi = sm.adp.tot[n];
        Mrow[(size_t)n * N + m] = GAMMA_C * Arow[(size_t)n * N + m] + bi * sm.adp.p[n][m];
    }
    __syncthreads();
}

// ---------------------------------------------------------------------------
// zr / cup: 32 rows/block, oc=tid&63, rg=tid>>6 -> 4 rows each.
// ---------------------------------------------------------------------------
__device__ void stage_rnn(SM& sm, const float* base, const float* P1, const float* P2,
                          size_t nn0, int tid)
{
    const size_t psC = (size_t)B * N * CC;
    const float2* c2  = (const float2*)(base + nn0 * CC);
    const float2* p1a = (const float2*)(P1 + nn0 * CC);
    const float2* p1b = (const float2*)(P1 + psC + nn0 * CC);
    const float2* p2a = (const float2*)(P2 + nn0 * CC);
    const float2* p2b = (const float2*)(P2 + psC + nn0 * CC);
    for (int l = tid; l < 32 * 33; l += 512) {
        int row = l / 33, k = (l - row * 33) * 2;
        *(float2*)&sm.zr.d[row][k] = c2[l];
        float2 a = p1a[l], b = p1b[l]; a.x += b.x; a.y += b.y;
        *(float2*)&sm.zr.d[row][66 + k] = a;
        float2 c = p2a[l], d = p2b[l]; c.x += d.x; c.y += d.y;
        *(float2*)&sm.zr.d[row][132 + k] = c;
    }
    __syncthreads();
}

__device__ void phase_zr(const Prm& p, SM& sm, int blk, int tid)
{
    const size_t nn0 = (size_t)blk * 32;
    stage_rnn(sm, p.comb, p.P1, p.P2, nn0, tid);
    int oc = tid & 63, rg = tid >> 6;
    float accz[4], accr[4];
#pragma unroll
    for (int rr = 0; rr < 4; ++rr) { accz[rr] = p.bgz[oc]; accr[rr] = p.bgr[oc]; }
#pragma unroll 2
    for (int sk = 0; sk < 198; ++sk) {
        float wz = p.Wgz[(size_t)sk * H + oc];
        float wr = p.Wgr[(size_t)sk * H + oc];
#pragma unroll
        for (int rr = 0; rr < 4; ++rr) {
            float v = sm.zr.d[rg * 4 + rr][sk];
            accz[rr] += v * wz; accr[rr] += v * wr;
        }
    }
#pragma unroll
    for (int rr = 0; rr < 4; ++rr) {
        int row = rg * 4 + rr;
        size_t nn = nn0 + row;
        float zv = fast_sigmoid(accz[rr]);
        float rv = fast_sigmoid(accr[rr]);
        p.z[nn * H + oc] = zv;
        p.comb2[nn * CC + F + oc] = rv * p.hidden[nn * H + oc];
        if (oc < F) p.comb2[nn * CC + oc] = sm.zr.d[row][oc];
    }
    __syncthreads();
}

__device__ void phase_cup(const Prm& p, SM& sm, int blk, int tid)
{
    const size_t nn0 = (size_t)blk * 32;
    stage_rnn(sm, p.comb2, p.P1, p.P2, nn0, tid);
    int oc = tid & 63, rg = tid >> 6;
    float acc[4];
#pragma unroll
    for (int rr = 0; rr < 4; ++rr) acc[rr] = p.bgc[oc];
#pragma unroll 2
    for (int sk = 0; sk < 198; ++sk) {
        float wc = p.Wgc[(size_t)sk * H + oc];
#pragma unroll
        for (int rr = 0; rr < 4; ++rr) acc[rr] += sm.zr.d[rg * 4 + rr][sk] * wc;
    }
#pragma unroll
    for (int rr = 0; rr < 4; ++rr) {
        size_t nn = nn0 + rg * 4 + rr;
        float cv = fast_tanh(acc[rr]);
        float zv = p.z[nn * H + oc];
        float ho = p.hidden[nn * H + oc];
        p.hidden[nn * H + oc] = zv * ho + (1.0f - zv) * cv;
    }
    __syncthreads();
}

// one full GRU step (phases + grid syncs)
__device__ void gru_step_dev(const Prm& p, SM& sm, cg::grid_group& g,
                             const float* graph, long gstride, int blk, int tid)
{
    // hyper: hh1 = a*h + h@K1 -> P1 ; hh2 = a*h + h@K2 -> P2 (independent)
    bmm_unit<0, false, false>(sm, p.P1, p.hidden, p.hidden, p.K1, blk, tid);
    bmm_unit<0, false, false>(sm, p.P2, p.hidden, p.hidden, p.K2, blk, tid);
    g.sync();
    phase_gsgt(p, sm, graph, gstride, blk, tid);
    g.sync();
    phase_adp(p, sm, blk, tid);
    g.sync();
    bmm_unit<2, false, true>(sm, p.P1, p.comb, p.comb, p.Mcomb, blk, tid);
    g.sync();
    bmm_unit<2, true, true>(sm, p.P2, p.comb, p.P1, p.Mcomb, blk, tid);
    g.sync();
    phase_zr(p, sm, blk, tid);
    g.sync();
    bmm_unit<2, false, true>(sm, p.P1, p.comb2, p.comb2, p.Mcomb, blk, tid);
    g.sync();
    bmm_unit<2, true, true>(sm, p.P2, p.comb2, p.P1, p.Mcomb, blk, tid);
    g.sync();
    phase_cup(p, sm, blk, tid);
    g.sync();
}

// qk precompute (grid-stride)
__device__ void phase_qk(const Prm& p, int blk, int tid)
{
    for (int idx = blk * 512 + tid; idx < B * N * DA + B * 4 * N * DA; idx += GSZ) {
        if (idx < B * N * DA) {
            int d = idx & 7;
            int n = (idx >> 3) & (N - 1);
            int b = idx >> 12;
            const float* tar = p.sample + (((size_t)b * T + (T - 1)) * N + n) * F;
            p.q[idx] = tar[0] * p.wq[d] + tar[1] * p.wq[DA + d] + p.attn_bias[d];
        } else {
            int j = idx - B * N * DA;
            int d = j & 7;
            int n = (j >> 3) & (N - 1);
            int t = (j >> 12) & 3;
            int b = j >> 14;
            const float* s = p.sample + (((size_t)b * T + (T - 4 + t)) * N + n) * F;
            p.kk[j] = s[0] * p.wk[d] + s[1] * p.wk[DA + d];
        }
    }
}

// scores+softmax: block -> (bt=blk>>2, 128 rows); wave per 16 rows, lane = 8 m's.
__device__ void phase_scores(const Prm& p, int blk, int tid)
{
    int bt = blk >> 2;
    int b = bt >> 2;
    int rbase = (blk & 3) * 128;
    int wid = tid >> 6, lane = tid & 63;
    const float* kkbt = p.kk + (size_t)bt * N * DA;
    float* attnbt = p.out_attn + (size_t)bt * N * N;
    float tr[8];
#pragma unroll
    for (int d = 0; d < 8; ++d) tr[d] = p.attn_trans[d];
    for (int i = 0; i < 16; ++i) {
        int n = rbase + wid * 16 + i;
        const float* qp = p.q + ((size_t)b * N + n) * DA;
        float4 qa = *(const float4*)qp, qb = *(const float4*)(qp + 4);
        float ev[8]; float ssum = 0.f;
#pragma unroll
        for (int k = 0; k < 8; ++k) {
            const float* kp = kkbt + (size_t)(k * 64 + lane) * DA;
            float4 ka = *(const float4*)kp, kb = *(const float4*)(kp + 4);
            float s = fast_tanh(qa.x + ka.x) * tr[0] + fast_tanh(qa.y + ka.y) * tr[1]
                    + fast_tanh(qa.z + ka.z) * tr[2] + fast_tanh(qa.w + ka.w) * tr[3]
                    + fast_tanh(qb.x + kb.x) * tr[4] + fast_tanh(qb.y + kb.y) * tr[5]
                    + fast_tanh(qb.z + kb.z) * tr[6] + fast_tanh(qb.w + kb.w) * tr[7];
            ev[k] = __expf(s);
            ssum += ev[k];
        }
        for (int o = 32; o > 0; o >>= 1) ssum += __shfl_down(ssum, o);
        ssum = __shfl(ssum, 0);
        float rinv = fast_rcp(ssum);
#pragma unroll
        for (int k = 0; k < 8; ++k)
            attnbt[(size_t)n * N + k * 64 + lane] = ev[k] * rinv;
    }
}

// TGN conv: 512 tiles over 256 blocks (2 each)
__device__ void phase_tgn(const Prm& p, SM& sm,
                          const float* hbase, long hsB, long hsT,
                          const float* xbase, long xsB, long xsT,
                          float* out, int blk, int tid)
{
    for (int u = blk; u < 512; u += 256) {
        int bt = u >> 3;
        int w0 = (u & 7) * 64;
        const float* hp = hbase + (size_t)(bt >> 2) * hsB + (size_t)(bt & 3) * hsT;
        const float* ap = p.out_attn + (size_t)bt * N * N;
        int wl = tid >> 3, c = tid & 1, vq = (tid >> 1) & 3;
        float acc = 0.f;
        for (int vt = 0; vt < 8; ++vt) {
            int v0 = vt * 64;
#pragma unroll
            for (int it = 0; it < 8; ++it) {
                int l = it * 512 + tid;
                int vr = l >> 6, wc = l & 63;
                size_t gi = (size_t)(v0 + vr) * N + (w0 + wc);
                sm.tgn.m[wc][vr] = p.A[gi] + ap[gi];
            }
            if (tid < 128) sm.tgn.h[tid >> 1][tid & 1] = hp[(size_t)(v0 + (tid >> 1)) * F + (tid & 1)];
            __syncthreads();
#pragma unroll
            for (int jj = 0; jj < 16; ++jj) {
                int j = vq * 16 + jj;
                acc += sm.tgn.m[wl][j] * sm.tgn.h[j][c];
            }
            __syncthreads();
        }
        acc += __shfl_xor(acc, 2);
        acc += __shfl_xor(acc, 4);
        if (vq == 0) {
            const float* xp = xbase + (size_t)(bt >> 2) * xsB + (size_t)(bt & 3) * xsT;
            out[((size_t)bt * N + w0 + wl) * F + c] =
                ALPHA_C * xp[(size_t)(w0 + wl) * F + c] + GAMMA_C * acc;
        }
    }
}

__device__ void phase_tgnout(const Prm& p, int blk, int tid)
{
    for (int idx = blk * 512 + tid; idx < B * N * TGN_OC; idx += GSZ) {
        int oc = idx & 31;
        int n = (idx >> 5) & (N - 1);
        int b = idx >> 14;
        float acc = 0.f;
        for (int t = 0; t < 4; ++t) {
            int bt = b * 4 + t;
            const float* s = p.sample + (((size_t)b * T + (T - 4 + t)) * N + n) * F;
            size_t r = ((size_t)bt * N + n) * F;
            float v = p.btg[oc];
            v += s[0] * p.Wt[0 * TGN_OC + oc] + s[1] * p.Wt[1 * TGN_OC + oc];
            v += p.th1[r] * p.Wt[2 * TGN_OC + oc] + p.th1[r + 1] * p.Wt[3 * TGN_OC + oc];
            v += p.th2[r] * p.Wt[4 * TGN_OC + oc] + p.th2[r + 1] * p.Wt[5 * TGN_OC + oc];
            acc += fmaxf(v, 0.0f);
        }
        p.tar32[idx] = acc;
    }
}

__device__ void phase_gat(const Prm& p, int blk, int tid)
{
    int idx = blk * 512 + tid;
    if (idx < B * N * F) {
        int f = idx & 1;
        int nn = idx >> 1;
        float acc = p.bsh[f];
        const float* tp = p.tar32 + (size_t)nn * TGN_OC;
        for (int k = 0; k < TGN_OC; ++k) acc += tp[k] * p.Wsh[(size_t)k * F + f];
        p.out_gat[idx] = acc;
    }
}

__device__ void phase_final(const Prm& p, int blk, int tid)
{
    int idx = blk * 512 + tid;
    if (idx < B * N * F) {
        int f = idx & 1;
        int nn = idx >> 1;
        const float* hp = p.hidden + (size_t)nn * H;
        const float* tp = p.tar32 + (size_t)nn * TGN_OC;
        float g = p.bl[f], fin = p.bm[f];
        for (int k = 0; k < H; ++k) g += hp[k] * p.Wl[(size_t)k * F + f];
        for (int k = 0; k < TGN_OC; ++k) fin += tp[k] * p.Wm[(size_t)k * F + f];
        for (int k = 0; k < H; ++k) fin += hp[k] * p.Wm[(size_t)(TGN_OC + k) * F + f];
        p.out_gru[idx] = g;
        p.out_fin[idx] = fin;
    }
}

// ---------------------------------------------------------------------------
// mega kernel
// ---------------------------------------------------------------------------
__global__ __launch_bounds__(512, 2) void mega_kernel(Prm p)
{
    cg::grid_group g = cg::this_grid();
    __shared__ SM sm;
    const int blk = blockIdx.x, tid = threadIdx.x;

    phase_init(p, sm, blk, tid);
    g.sync();

    for (int step = 0; step < 5; ++step) {
        const float* graph = p.sample + (size_t)(4 * step) * N * F;
        gru_step_dev(p, sm, g, graph, (long)T * N * F, blk, tid);
    }

    phase_qk(p, blk, tid);
    g.sync();
    phase_scores(p, blk, tid);
    g.sync();
    const float* srcbase = p.sample + (size_t)(T - 4) * N * F;
    phase_tgn(p, sm, srcbase, (long)T * N * F, (long)N * F,
              srcbase, (long)T * N * F, (long)N * F, p.th1, blk, tid);
    g.sync();
    phase_tgn(p, sm, p.th1, (long)4 * N * F, (long)N * F,
              srcbase, (long)T * N * F, (long)N * F, p.th2, blk, tid);
    g.sync();
    phase_tgnout(p, blk, tid);
    g.sync();
    phase_gat(p, blk, tid);
    g.sync();

    gru_step_dev(p, sm, g, p.out_gat, (long)N * F, blk, tid);

    phase_final(p, blk, tid);
}

// ---------------------------------------------------------------------------
// Host
// ---------------------------------------------------------------------------
extern "C" void kernel_launch(void* const* d_in, const int* in_sizes, int n_in,
                              void* d_out, int out_size, void* d_ws, size_t ws_size,
                              hipStream_t stream)
{
    (void)in_sizes; (void)n_in; (void)out_size; (void)ws_size;
    Prm p;
    p.sample = (const float*)d_in[0];
    p.A      = (const float*)d_in[1];
    p.wq     = (const float*)d_in[2];
    p.wk     = (const float*)d_in[3];
    p.attn_bias  = (const float*)d_in[4];
    p.attn_trans = (const float*)d_in[5];
    p.Wt  = (const float*)d_in[6];
    p.btg = (const float*)d_in[7];
    p.Wa1 = (const float*)d_in[8];
    p.ba1 = (const float*)d_in[9];
    p.Wa2 = (const float*)d_in[10];
    p.ba2 = (const float*)d_in[11];
    p.Wsrc = (const float*)d_in[12];
    p.bsrc = (const float*)d_in[13];
    p.Wtgt = (const float*)d_in[14];
    p.btgt = (const float*)d_in[15];
    p.Wgz = (const float*)d_in[16];
    p.bgz = (const float*)d_in[17];
    p.Wgr = (const float*)d_in[18];
    p.bgr = (const float*)d_in[19];
    p.Wgc = (const float*)d_in[20];
    p.bgc = (const float*)d_in[21];
    p.Wsh = (const float*)d_in[22];
    p.bsh = (const float*)d_in[23];
    p.Wl  = (const float*)d_in[24];
    p.bl  = (const float*)d_in[25];
    p.Wm  = (const float*)d_in[26];
    p.bm  = (const float*)d_in[27];

    float* ws = (float*)d_ws;
    size_t off = 0;
    auto alloc = [&](size_t nelem) { float* r = ws + off; off += nelem; return r; };
    p.hidden = alloc((size_t)B * N * H);
    p.nvs    = alloc((size_t)B * N * E);
    p.nvt    = alloc((size_t)B * N * E);
    p.Mcomb  = alloc((size_t)B * N * N);
    p.K1     = alloc((size_t)N * N);
    p.K2     = alloc((size_t)N * N);
    p.comb   = alloc((size_t)B * N * CC);
    p.comb2  = alloc((size_t)B * N * CC);
    p.z      = alloc((size_t)B * N * H);
    p.P1     = alloc((size_t)2 * B * N * CC);
    p.P2     = alloc((size_t)2 * B * N * CC);
    p.q      = alloc((size_t)B * N * DA);
    p.kk     = alloc((size_t)B * 4 * N * DA);
    p.th1    = alloc((size_t)B * 4 * N * F);
    p.th2    = alloc((size_t)B * 4 * N * F);
    p.tar32  = alloc((size_t)B * N * TGN_OC);

    float* out = (float*)d_out;
    p.out_gat  = out;
    p.out_gru  = out + (size_t)B * N * F;
    p.out_fin  = out + (size_t)2 * B * N * F;
    p.out_attn = out + (size_t)3 * B * N * F;

    void* args[] = { (void*)&p };
    hipLaunchCooperativeKernel((const void*)mega_kernel, dim3(256), dim3(512),
                               args, 0, stream);
}

// Round 5
// 1583.885 us; speedup vs baseline: 2.6558x; 2.6558x over previous
//
#include <hip/hip_runtime.h>

#define ALPHA_C 0.05f
#define BETA_C  0.95f
#define GAMMA_C 0.95f

constexpr int B = 16, T = 24, N = 512, F = 2, H = 64, E = 16;
constexpr int DA = 8;
constexpr int CC = F + H;    // 66
constexpr int TGN_OC = 32;
constexpr int NPART = 4;     // v-quarter partials

__device__ __forceinline__ float fast_rcp(float x) { return __builtin_amdgcn_rcpf(x); }
__device__ __forceinline__ float fast_tanh(float x) {
    return 1.0f - 2.0f * fast_rcp(__expf(2.0f * x) + 1.0f);
}
__device__ __forceinline__ float fast_sigmoid(float x) {
    return fast_rcp(1.0f + __expf(-x));
}

// K1 = GAMMA*A (one-time)
__global__ void scaleA_kernel(const float* __restrict__ A, float* __restrict__ K1)
{
    int i = blockIdx.x * 256 + threadIdx.x;
    K1[i] = GAMMA_C * A[i];
}

// K2 = GAMMA*ALPHA*A + GAMMA^2 * A@A (one-time). Grid (32,32), 256 thr,
// 16x16 out tile per block, K staged in 256-chunks.
__global__ __launch_bounds__(256) void k2_kernel(const float* __restrict__ A,
                                                 float* __restrict__ K2)
{
    __shared__ float rows[16][258];
    __shared__ float cols[256][17];
    const int tid = threadIdx.x;
    const int r0 = blockIdx.y * 16, c0 = blockIdx.x * 16;
    const int rr = tid >> 4, cc = tid & 15;
    float acc = 0.f;
    for (int k0 = 0; k0 < N; k0 += 256) {
#pragma unroll
        for (int it = 0; it < 4; ++it) {
            int l = it * 256 + tid;
            int row = l >> 6, k4 = (l & 63) << 2;
            *(float4*)&rows[row][k4] = *(const float4*)(A + (size_t)(r0 + row) * N + k0 + k4);
        }
#pragma unroll
        for (int it = 0; it < 4; ++it) {
            int l = it * 256 + tid;
            int k = l >> 2, c4 = (l & 3) << 2;
            *(float4*)&cols[k][c4] = *(const float4*)(A + (size_t)(k0 + k) * N + c0 + c4);
        }
        __syncthreads();
#pragma unroll 8
        for (int k = 0; k < 256; ++k) acc += rows[rr][k] * cols[k][cc];
        __syncthreads();
    }
    size_t i = (size_t)(r0 + rr) * N + c0 + cc;
    K2[i] = GAMMA_C * ALPHA_C * A[i] + GAMMA_C * GAMMA_C * acc;
}

// ---------------------------------------------------------------------------
// bmm core: out_part[vq][b,w,c] = (vq==0 ? ALPHA*x : 0) + sum_{v in quarter} M[v,w]*in[b,v,c]
// 256 thr, 64x64(+2) tile, 4x4 per thread (round-3 proven core).
// ---------------------------------------------------------------------------
template<int GCOLS, bool INSUM, bool MPB>
__device__ __forceinline__ void bmm_core(
    float* __restrict__ out, const float* __restrict__ x, const float* __restrict__ in,
    const float* __restrict__ M, int b, int w0, int vq, int tid,
    float (*sh_m)[68], float (*sh_h)[68])
{
    constexpr int Crow = 64 + GCOLS;
    const size_t pstr = (size_t)B * N * Crow;
    const int cg = tid & 15;
    const int wg = tid >> 4;

    float acc[4][4];
#pragma unroll
    for (int r = 0; r < 4; ++r)
#pragma unroll
        for (int c = 0; c < 4; ++c) acc[r][c] = 0.0f;
    float ag[4] = {0.f, 0.f, 0.f, 0.f};

    const float* Mb = M + (MPB ? (size_t)b * N * N : 0);
    const float* inb = in + (size_t)b * N * Crow;

    for (int vt = 0; vt < 2; ++vt) {
        const int v0 = vq * 128 + vt * 64;
#pragma unroll
        for (int it = 0; it < 4; ++it) {
            int l = it * 256 + tid;
            int row = l >> 4, c4 = (l & 15) << 2;
            *(float4*)&sh_m[row][c4] =
                *(const float4*)(Mb + (size_t)(v0 + row) * N + w0 + c4);
        }
        if (GCOLS == 2) {
            const float2* h0 = (const float2*)(inb + (size_t)v0 * Crow);
            for (int l = tid; l < 64 * 33; l += 256) {
                int row = l / 33, k = (l - row * 33) * 2;
                float2 v = h0[l];
                if (INSUM) {
#pragma unroll
                    for (int j = 1; j < NPART; ++j) {
                        float2 w = ((const float2*)(inb + (size_t)j * pstr + (size_t)v0 * Crow))[l];
                        v.x += w.x; v.y += w.y;
                    }
                }
                *(float2*)&sh_h[row][k] = v;
            }
        } else {
            const float4* h0 = (const float4*)(inb + (size_t)v0 * Crow);
#pragma unroll
            for (int it = 0; it < 4; ++it) {
                int l = it * 256 + tid;
                int row = l >> 4, k = (l & 15) << 2;
                float4 v = h0[l];
                if (INSUM) {
#pragma unroll
                    for (int j = 1; j < NPART; ++j) {
                        float4 w = ((const float4*)(inb + (size_t)j * pstr + (size_t)v0 * Crow))[l];
                        v.x += w.x; v.y += w.y; v.z += w.z; v.w += w.w;
                    }
                }
                *(float4*)&sh_h[row][k] = v;
            }
        }
        __syncthreads();
#pragma unroll 8
        for (int j = 0; j < 64; ++j) {
            float4 mv = *(const float4*)&sh_m[j][wg << 2];
            float4 hv = *(const float4*)&sh_h[j][cg << 2];
            acc[0][0] += mv.x * hv.x; acc[0][1] += mv.x * hv.y; acc[0][2] += mv.x * hv.z; acc[0][3] += mv.x * hv.w;
            acc[1][0] += mv.y * hv.x; acc[1][1] += mv.y * hv.y; acc[1][2] += mv.y * hv.z; acc[1][3] += mv.y * hv.w;
            acc[2][0] += mv.z * hv.x; acc[2][1] += mv.z * hv.y; acc[2][2] += mv.z * hv.z; acc[2][3] += mv.z * hv.w;
            acc[3][0] += mv.w * hv.x; acc[3][1] += mv.w * hv.y; acc[3][2] += mv.w * hv.z; acc[3][3] += mv.w * hv.w;
            if (GCOLS > 0 && cg < GCOLS) {
                float gv = sh_h[j][64 + cg];
                ag[0] += mv.x * gv; ag[1] += mv.y * gv; ag[2] += mv.z * gv; ag[3] += mv.w * gv;
            }
        }
        __syncthreads();
    }
    float* outp = out + (size_t)vq * pstr + (size_t)b * N * Crow;
    const float* xb = x + (size_t)b * N * Crow;
#pragma unroll
    for (int r = 0; r < 4; ++r) {
        const int w = w0 + (wg << 2) + r;
        const size_t base = (size_t)w * Crow + (cg << 2);
        if (GCOLS == 2) {
            float o0 = acc[r][0], o1 = acc[r][1], o2 = acc[r][2], o3 = acc[r][3];
            if (vq == 0) {
                o0 += ALPHA_C * xb[base];     o1 += ALPHA_C * xb[base + 1];
                o2 += ALPHA_C * xb[base + 2]; o3 += ALPHA_C * xb[base + 3];
            }
            float2 lo = {o0, o1}, hi = {o2, o3};
            *(float2*)(outp + base) = lo;
            *(float2*)(outp + base + 2) = hi;
            if (cg < GCOLS) {
                size_t gb = (size_t)w * Crow + 64 + cg;
                float v = ag[r];
                if (vq == 0) v += ALPHA_C * xb[gb];
                outp[gb] = v;
            }
        } else {
            float4 ov = {acc[r][0], acc[r][1], acc[r][2], acc[r][3]};
            if (vq == 0) {
                float4 xv = *(const float4*)(xb + base);
                ov.x += ALPHA_C * xv.x; ov.y += ALPHA_C * xv.y;
                ov.z += ALPHA_C * xv.z; ov.w += ALPHA_C * xv.w;
            }
            *(float4*)(outp + base) = ov;
        }
    }
}

// rnn bmm: grid (8, 4, B)
template<bool INSUM>
__global__ __launch_bounds__(256) void bmm4_kernel(
    float* __restrict__ out, const float* __restrict__ x, const float* __restrict__ in,
    const float* __restrict__ M)
{
    __shared__ float sh_m[64][68];
    __shared__ float sh_h[64][68];
    bmm_core<2, INSUM, true>(out, x, in, M, blockIdx.z, blockIdx.x * 64, blockIdx.y,
                             threadIdx.x, sh_m, sh_h);
}

// fused hyper: grid (8, 8, B): y = vq(0..3) | which(0..1)<<2. Both read hidden.
__global__ __launch_bounds__(256) void hyper_kernel(
    float* __restrict__ P1, float* __restrict__ P2, const float* __restrict__ hidden,
    const float* __restrict__ K1, const float* __restrict__ K2)
{
    __shared__ float sh_m[64][68];
    __shared__ float sh_h[64][68];
    int vq = blockIdx.y & 3, which = blockIdx.y >> 2;
    float* out = which ? P2 : P1;
    const float* M = which ? K2 : K1;
    bmm_core<0, false, false>(out, hidden, hidden, M, blockIdx.z, blockIdx.x * 64, vq,
                              threadIdx.x, sh_m, sh_h);
}

// ---------------------------------------------------------------------------
// gsgt: 16-row slabs (grid 512), 256 thr: one (row,e) per thread.
// Stages [hidden | sum4 P1 | sum4 P2]; writes nv_s/nv_t.
// ---------------------------------------------------------------------------
__global__ __launch_bounds__(256) void gsgt4_kernel(
    const float* __restrict__ hidden, const float* __restrict__ P1, const float* __restrict__ P2,
    const float* __restrict__ Wa1, const float* __restrict__ ba1,
    const float* __restrict__ Wa2, const float* __restrict__ ba2,
    const float* __restrict__ graph, long gstride,
    const float* __restrict__ Wsrc, const float* __restrict__ bsrc,
    const float* __restrict__ Wtgt, const float* __restrict__ btgt,
    float* __restrict__ nv_s, float* __restrict__ nv_t)
{
    constexpr size_t psH = (size_t)B * N * H;
    __shared__ float sh[16][194];
    const int tid = threadIdx.x;
    const int e = tid & 15;
    const int row = tid >> 4;     // 0..15
    const size_t nn0 = (size_t)blockIdx.x * 16;
    // stage: one float4 per thread per segment (16 rows x 16 f4 = 256)
    {
        int f4 = ((int)(nn0) + row) * 16 + e;   // f4 index into (B*N,64) arrays
        float4 v = ((const float4*)hidden)[f4];
        *(float4*)&sh[row][e << 2] = v;
        float4 a = ((const float4*)P1)[f4];
#pragma unroll
        for (int j = 1; j < NPART; ++j) {
            float4 w = ((const float4*)(P1 + (size_t)j * psH))[f4];
            a.x += w.x; a.y += w.y; a.z += w.z; a.w += w.w;
        }
        *(float4*)&sh[row][64 + (e << 2)] = a;
        float4 c = ((const float4*)P2)[f4];
#pragma unroll
        for (int j = 1; j < NPART; ++j) {
            float4 w = ((const float4*)(P2 + (size_t)j * psH))[f4];
            c.x += w.x; c.y += w.y; c.z += w.z; c.w += w.w;
        }
        *(float4*)&sh[row][128 + (e << 2)] = c;
    }
    __syncthreads();
    float gs = ba1[e], gt = ba2[e];
#pragma unroll 4
    for (int sk = 0; sk < 192; ++sk) {
        float v = sh[row][sk];
        gs += v * Wa1[(size_t)sk * E + e];
        gt += v * Wa2[(size_t)sk * E + e];
    }
    size_t nn = nn0 + row;
    int b = (int)(nn >> 9), n = (int)(nn & (N - 1));
    const float* g = graph + (size_t)b * gstride + (size_t)n * F;
    float g0 = g[0], g1 = g[1];
    float es = g0 * Wsrc[e] + g1 * Wsrc[E + e] + bsrc[e];
    float et = g0 * Wtgt[e] + g1 * Wtgt[E + e] + btgt[e];
    nv_s[nn * E + e] = fast_tanh(2.0f * es * gs);
    nv_t[nn * E + e] = fast_tanh(2.0f * et * gt);
}

// ---------------------------------------------------------------------------
// adp (round-3 proven): 4 rows/block, grid (128,16), 512 thr. Writes
// Mcomb = GAMMA*A + (BETA/rowsum)*p and comb = [graph|hidden].
// ---------------------------------------------------------------------------
__global__ __launch_bounds__(512) void adp3_kernel(
    const float* __restrict__ nv_s, const float* __restrict__ nv_t,
    const float* __restrict__ A,
    const float* __restrict__ hidden, const float* __restrict__ graph, long gstride,
    float* __restrict__ Mcomb, float* __restrict__ comb)
{
    __shared__ float red[8][4];
    __shared__ float tot[4];
    const int m = threadIdx.x;
    const int n0 = blockIdx.x * 4;
    const int b = blockIdx.y;
    const float4* sm = (const float4*)(nv_s + ((size_t)b * N + m) * E);
    const float4* tm = (const float4*)(nv_t + ((size_t)b * N + m) * E);
    const float4* sn = (const float4*)(nv_s + ((size_t)b * N + n0) * E);
    const float4* tn = (const float4*)(nv_t + ((size_t)b * N + n0) * E);
    float a1[4] = {0.f,0.f,0.f,0.f}, a2[4] = {0.f,0.f,0.f,0.f};
#pragma unroll
    for (int dd = 0; dd < 4; ++dd) {
        float4 smv = sm[dd], tmv = tm[dd];
#pragma unroll
        for (int r = 0; r < 4; ++r) {
            float4 snv = sn[r * 4 + dd], tnv = tn[r * 4 + dd];
            a1[r] += snv.x * tmv.x + snv.y * tmv.y + snv.z * tmv.z + snv.w * tmv.w;
            a2[r] += tnv.x * smv.x + tnv.y * smv.y + tnv.z * smv.z + tnv.w * smv.w;
        }
    }
    float p[4];
#pragma unroll
    for (int r = 0; r < 4; ++r) {
        float pv = fmaxf(fast_tanh(2.0f * (a1[r] - a2[r])), 0.0f);
        if (m == n0 + r) pv += 1.0f;
        p[r] = pv;
    }
    float sr[4] = {p[0], p[1], p[2], p[3]};
    for (int o = 32; o > 0; o >>= 1) {
#pragma unroll
        for (int r = 0; r < 4; ++r) sr[r] += __shfl_down(sr[r], o);
    }
    int wid = m >> 6, lane = m & 63;
    if (lane == 0) {
#pragma unroll
        for (int r = 0; r < 4; ++r) red[wid][r] = sr[r];
    }
    __syncthreads();
    if (m < 4) {
        float t = 0.f;
        for (int i = 0; i < 8; ++i) t += red[i][m];
        tot[m] = BETA_C * fast_rcp(t);
    }
    __syncthreads();
#pragma unroll
    for (int r = 0; r < 4; ++r)
        Mcomb[((size_t)b * N + n0 + r) * N + m] =
            GAMMA_C * A[(size_t)(n0 + r) * N + m] + p[r] * tot[r];
    if (m < 4 * CC) {
        int r = m / CC, k = m - r * CC;
        size_t nn = (size_t)b * N + n0 + r;
        float v;
        if (k < F) v = graph[(size_t)b * gstride + (size_t)(n0 + r) * F + k];
        else       v = hidden[nn * H + (k - F)];
        comb[nn * CC + k] = v;
    }
}

// ---------------------------------------------------------------------------
// zr / cup: 16-row slabs (grid 512), 256 thr, sum 4 partials.
// ---------------------------------------------------------------------------
__device__ __forceinline__ void stage_rnn4(float (*sh)[200], const float* base,
                                           const float* P1, const float* P2,
                                           size_t nn0, int tid)
{
    constexpr size_t psC = (size_t)B * N * CC;
    const float2* c2 = (const float2*)(base + nn0 * CC);
    for (int l = tid; l < 16 * 33; l += 256) {
        int row = l / 33, k = (l - row * 33) * 2;
        *(float2*)&sh[row][k] = c2[l];
        float2 a = ((const float2*)(P1 + nn0 * CC))[l];
#pragma unroll
        for (int j = 1; j < NPART; ++j) {
            float2 w = ((const float2*)(P1 + (size_t)j * psC + nn0 * CC))[l];
            a.x += w.x; a.y += w.y;
        }
        *(float2*)&sh[row][66 + k] = a;
        float2 c = ((const float2*)(P2 + nn0 * CC))[l];
#pragma unroll
        for (int j = 1; j < NPART; ++j) {
            float2 w = ((const float2*)(P2 + (size_t)j * psC + nn0 * CC))[l];
            c.x += w.x; c.y += w.y;
        }
        *(float2*)&sh[row][132 + k] = c;
    }
    __syncthreads();
}

__global__ __launch_bounds__(256) void zr4_kernel(
    const float* __restrict__ comb, const float* __restrict__ P1, const float* __restrict__ P2,
    const float* __restrict__ Wgz, const float* __restrict__ bgz,
    const float* __restrict__ Wgr, const float* __restrict__ bgr,
    const float* __restrict__ hidden,
    float* __restrict__ z, float* __restrict__ comb2)
{
    __shared__ float sh[16][200];
    const int tid = threadIdx.x;
    const int oc = tid & 63;
    const int rg = tid >> 6;
    const size_t nn0 = (size_t)blockIdx.x * 16;
    stage_rnn4(sh, comb, P1, P2, nn0, tid);
    float accz[4], accr[4];
#pragma unroll
    for (int rr = 0; rr < 4; ++rr) { accz[rr] = bgz[oc]; accr[rr] = bgr[oc]; }
#pragma unroll 2
    for (int sk = 0; sk < 198; ++sk) {
        float wz = Wgz[(size_t)sk * H + oc];
        float wr = Wgr[(size_t)sk * H + oc];
#pragma unroll
        for (int rr = 0; rr < 4; ++rr) {
            float v = sh[rg * 4 + rr][sk];
            accz[rr] += v * wz; accr[rr] += v * wr;
        }
    }
#pragma unroll
    for (int rr = 0; rr < 4; ++rr) {
        int row = rg * 4 + rr;
        size_t nn = nn0 + row;
        float zv = fast_sigmoid(accz[rr]);
        float rv = fast_sigmoid(accr[rr]);
        z[nn * H + oc] = zv;
        comb2[nn * CC + F + oc] = rv * hidden[nn * H + oc];
        if (oc < F) comb2[nn * CC + oc] = sh[row][oc];
    }
}

__global__ __launch_bounds__(256) void cup4_kernel(
    const float* __restrict__ comb2, const float* __restrict__ P1, const float* __restrict__ P2,
    const float* __restrict__ Wgc, const float* __restrict__ bgc,
    const float* __restrict__ z, float* __restrict__ hidden)
{
    __shared__ float sh[16][200];
    const int tid = threadIdx.x;
    const int oc = tid & 63;
    const int rg = tid >> 6;
    const size_t nn0 = (size_t)blockIdx.x * 16;
    stage_rnn4(sh, comb2, P1, P2, nn0, tid);
    float acc[4];
#pragma unroll
    for (int rr = 0; rr < 4; ++rr) acc[rr] = bgc[oc];
#pragma unroll 2
    for (int sk = 0; sk < 198; ++sk) {
        float wc = Wgc[(size_t)sk * H + oc];
#pragma unroll
        for (int rr = 0; rr < 4; ++rr) acc[rr] += sh[rg * 4 + rr][sk] * wc;
    }
#pragma unroll
    for (int rr = 0; rr < 4; ++rr) {
        size_t nn = nn0 + rg * 4 + rr;
        float cv = fast_tanh(acc[rr]);
        float zv = z[nn * H + oc];
        float ho = hidden[nn * H + oc];
        hidden[nn * H + oc] = zv * ho + (1.0f - zv) * cv;
    }
}

// q/k precompute
__global__ void qk_kernel(const float* __restrict__ sample,
                          const float* __restrict__ wq, const float* __restrict__ wk,
                          const float* __restrict__ attn_bias,
                          float* __restrict__ q, float* __restrict__ kk)
{
    int idx = blockIdx.x * 256 + threadIdx.x;
    if (idx < B * N * DA) {
        int d = idx & 7;
        int n = (idx >> 3) & (N - 1);
        int b = idx >> 12;
        const float* tar = sample + (((size_t)b * T + (T - 1)) * N + n) * F;
        q[idx] = tar[0] * wq[d] + tar[1] * wq[DA + d] + attn_bias[d];
    } else {
        int j = idx - B * N * DA;
        int d = j & 7;
        int n = (j >> 3) & (N - 1);
        int t = (j >> 12) & 3;
        int b = j >> 14;
        const float* s = sample + (((size_t)b * T + (T - 4 + t)) * N + n) * F;
        kk[j] = s[0] * wk[d] + s[1] * wk[DA + d];
    }
}

// scores v2: grid (8, 64), 256 thr; wave handles 16 rows, lane covers 8 m's.
__global__ __launch_bounds__(256) void scores2_kernel(
    const float* __restrict__ q, const float* __restrict__ kk,
    const float* __restrict__ trans, float* __restrict__ attn)
{
    int bt = blockIdx.y;
    int b = bt >> 2;
    int rbase = blockIdx.x * 64;
    int wid = threadIdx.x >> 6, lane = threadIdx.x & 63;
    const float* kkbt = kk + (size_t)bt * N * DA;
    float* attnbt = attn + (size_t)bt * N * N;
    float tr[8];
#pragma unroll
    for (int d = 0; d < 8; ++d) tr[d] = trans[d];
    for (int i = 0; i < 16; ++i) {
        int n = rbase + wid * 16 + i;
        const float* qp = q + ((size_t)b * N + n) * DA;
        float4 qa = *(const float4*)qp, qb = *(const float4*)(qp + 4);
        float ev[8]; float ssum = 0.f;
#pragma unroll
        for (int k = 0; k < 8; ++k) {
            const float* kp = kkbt + (size_t)(k * 64 + lane) * DA;
            float4 ka = *(const float4*)kp, kb = *(const float4*)(kp + 4);
            float s = fast_tanh(qa.x + ka.x) * tr[0] + fast_tanh(qa.y + ka.y) * tr[1]
                    + fast_tanh(qa.z + ka.z) * tr[2] + fast_tanh(qa.w + ka.w) * tr[3]
                    + fast_tanh(qb.x + kb.x) * tr[4] + fast_tanh(qb.y + kb.y) * tr[5]
                    + fast_tanh(qb.z + kb.z) * tr[6] + fast_tanh(qb.w + kb.w) * tr[7];
            ev[k] = __expf(s);
            ssum += ev[k];
        }
        for (int o = 32; o > 0; o >>= 1) ssum += __shfl_down(ssum, o);
        ssum = __shfl(ssum, 0);
        float rinv = fast_rcp(ssum);
#pragma unroll
        for (int k = 0; k < 8; ++k)
            attnbt[(size_t)n * N + k * 64 + lane] = ev[k] * rinv;
    }
}

// TGN conv v2: grid (8, 64), 256 thr; wl=tid>>2 (64 rows), c=tid&1, vh=(tid>>1)&1.
__global__ __launch_bounds__(256) void tgn2_kernel(
    const float* __restrict__ A, const float* __restrict__ attn,
    const float* __restrict__ hbase, long hsB, long hsT,
    const float* __restrict__ xbase, long xsB, long xsT,
    float* __restrict__ out)
{
    __shared__ float sh_m[64][65];
    __shared__ float sh_h[64][2];
    int bt = blockIdx.y;
    int w0 = blockIdx.x * 64;
    int tid = threadIdx.x;
    int wl = tid >> 2, c = tid & 1, vh = (tid >> 1) & 1;
    const float* hp = hbase + (size_t)(bt >> 2) * hsB + (size_t)(bt & 3) * hsT;
    const float* ap = attn + (size_t)bt * N * N;
    float acc = 0.f;
    for (int vt = 0; vt < 8; ++vt) {
        int v0 = vt * 64;
#pragma unroll
        for (int it = 0; it < 16; ++it) {
            int l = it * 256 + tid;
            int vr = l >> 6, wc = l & 63;
            size_t gi = (size_t)(v0 + vr) * N + (w0 + wc);
            sh_m[wc][vr] = A[gi] + ap[gi];
        }
        if (tid < 128) sh_h[tid >> 1][tid & 1] = hp[(size_t)(v0 + (tid >> 1)) * F + (tid & 1)];
        __syncthreads();
#pragma unroll
        for (int jj = 0; jj < 32; ++jj) {
            int j = vh * 32 + jj;
            acc += sh_m[wl][j] * sh_h[j][c];
        }
        __syncthreads();
    }
    acc += __shfl_xor(acc, 2);
    if (vh == 0) {
        const float* xp = xbase + (size_t)(bt >> 2) * xsB + (size_t)(bt & 3) * xsT;
        out[((size_t)bt * N + w0 + wl) * F + c] =
            ALPHA_C * xp[(size_t)(w0 + wl) * F + c] + GAMMA_C * acc;
    }
}

__global__ void tgn_out_kernel(const float* __restrict__ sample,
                               const float* __restrict__ th1, const float* __restrict__ th2,
                               const float* __restrict__ Wt, const float* __restrict__ bt_,
                               float* __restrict__ tar32)
{
    int idx = blockIdx.x * 256 + threadIdx.x;
    int oc = idx & 31;
    int n = (idx >> 5) & (N - 1);
    int b = idx >> 14;
    float acc = 0.f;
    for (int t = 0; t < 4; ++t) {
        int bt = b * 4 + t;
        const float* s = sample + (((size_t)b * T + (T - 4 + t)) * N + n) * F;
        size_t r = ((size_t)bt * N + n) * F;
        float v = bt_[oc];
        v += s[0] * Wt[0 * TGN_OC + oc] + s[1] * Wt[1 * TGN_OC + oc];
        v += th1[r] * Wt[2 * TGN_OC + oc] + th1[r + 1] * Wt[3 * TGN_OC + oc];
        v += th2[r] * Wt[4 * TGN_OC + oc] + th2[r + 1] * Wt[5 * TGN_OC + oc];
        acc += fmaxf(v, 0.0f);
    }
    tar32[idx] = acc;
}

__global__ void gat_kernel(const float* __restrict__ tar32,
                           const float* __restrict__ Ws, const float* __restrict__ bs,
                           float* __restrict__ out0)
{
    int idx = blockIdx.x * 256 + threadIdx.x;
    int f = idx & 1;
    int nn = idx >> 1;
    float acc = bs[f];
    const float* tp = tar32 + (size_t)nn * TGN_OC;
    for (int k = 0; k < TGN_OC; ++k) acc += tp[k] * Ws[(size_t)k * F + f];
    out0[idx] = acc;
}

__global__ void final_kernel(const float* __restrict__ hidden, const float* __restrict__ tar32,
                             const float* __restrict__ Wl, const float* __restrict__ bl,
                             const float* __restrict__ Wm, const float* __restrict__ bm,
                             float* __restrict__ dout_gru, float* __restrict__ dout_fin)
{
    int idx = blockIdx.x * 256 + threadIdx.x;
    int f = idx & 1;
    int nn = idx >> 1;
    const float* hp = hidden + (size_t)nn * H;
    const float* tp = tar32 + (size_t)nn * TGN_OC;
    float g = bl[f], fin = bm[f];
    for (int k = 0; k < H; ++k) g += hp[k] * Wl[(size_t)k * F + f];
    for (int k = 0; k < TGN_OC; ++k) fin += tp[k] * Wm[(size_t)k * F + f];
    for (int k = 0; k < H; ++k) fin += hp[k] * Wm[(size_t)(TGN_OC + k) * F + f];
    dout_gru[idx] = g;
    dout_fin[idx] = fin;
}

// ---------------------------------------------------------------------------
// Host side
// ---------------------------------------------------------------------------
namespace {
struct Ptrs {
    const float *sample, *A, *wq, *wk, *attn_bias, *attn_trans, *Wt, *bt_;
    const float *Wa1, *ba1, *Wa2, *ba2, *Wsrc, *bsrc, *Wtgt, *btgt;
    const float *Wgz, *bgz, *Wgr, *bgr, *Wgc, *bgc, *Wsh, *bsh, *Wl, *bl, *Wm, *bm;
    float *hidden, *nvs, *nvt, *Mcomb, *K1, *K2, *comb, *comb2, *z, *P1, *P2;
    float *q, *kk, *th1, *th2, *tar32;
};

void gru_step(hipStream_t stream, const Ptrs& p, const float* graph, long gstride)
{
    dim3 bg(8, NPART, B);   // 512 blocks
    hyper_kernel<<<dim3(8, 2 * NPART, B), 256, 0, stream>>>(p.P1, p.P2, p.hidden, p.K1, p.K2);
    gsgt4_kernel<<<B * N / 16, 256, 0, stream>>>(
        p.hidden, p.P1, p.P2, p.Wa1, p.ba1, p.Wa2, p.ba2, graph, gstride,
        p.Wsrc, p.bsrc, p.Wtgt, p.btgt, p.nvs, p.nvt);
    adp3_kernel<<<dim3(N / 4, B), 512, 0, stream>>>(
        p.nvs, p.nvt, p.A, p.hidden, graph, gstride, p.Mcomb, p.comb);
    bmm4_kernel<false><<<bg, 256, 0, stream>>>(p.P1, p.comb, p.comb, p.Mcomb);
    bmm4_kernel<true><<<bg, 256, 0, stream>>>(p.P2, p.comb, p.P1, p.Mcomb);
    zr4_kernel<<<B * N / 16, 256, 0, stream>>>(
        p.comb, p.P1, p.P2, p.Wgz, p.bgz, p.Wgr, p.bgr, p.hidden, p.z, p.comb2);
    bmm4_kernel<false><<<bg, 256, 0, stream>>>(p.P1, p.comb2, p.comb2, p.Mcomb);
    bmm4_kernel<true><<<bg, 256, 0, stream>>>(p.P2, p.comb2, p.P1, p.Mcomb);
    cup4_kernel<<<B * N / 16, 256, 0, stream>>>(
        p.comb2, p.P1, p.P2, p.Wgc, p.bgc, p.z, p.hidden);
}
}  // namespace

extern "C" void kernel_launch(void* const* d_in, const int* in_sizes, int n_in,
                              void* d_out, int out_size, void* d_ws, size_t ws_size,
                              hipStream_t stream)
{
    (void)in_sizes; (void)n_in; (void)out_size; (void)ws_size;
    Ptrs p;
    p.sample = (const float*)d_in[0];
    p.A      = (const float*)d_in[1];
    p.wq     = (const float*)d_in[2];
    p.wk     = (const float*)d_in[3];
    p.attn_bias  = (const float*)d_in[4];
    p.attn_trans = (const float*)d_in[5];
    p.Wt  = (const float*)d_in[6];
    p.bt_ = (const float*)d_in[7];
    p.Wa1 = (const float*)d_in[8];
    p.ba1 = (const float*)d_in[9];
    p.Wa2 = (const float*)d_in[10];
    p.ba2 = (const float*)d_in[11];
    p.Wsrc = (const float*)d_in[12];
    p.bsrc = (const float*)d_in[13];
    p.Wtgt = (const float*)d_in[14];
    p.btgt = (const float*)d_in[15];
    p.Wgz = (const float*)d_in[16];
    p.bgz = (const float*)d_in[17];
    p.Wgr = (const float*)d_in[18];
    p.bgr = (const float*)d_in[19];
    p.Wgc = (const float*)d_in[20];
    p.bgc = (const float*)d_in[21];
    p.Wsh = (const float*)d_in[22];
    p.bsh = (const float*)d_in[23];
    p.Wl  = (const float*)d_in[24];
    p.bl  = (const float*)d_in[25];
    p.Wm  = (const float*)d_in[26];
    p.bm  = (const float*)d_in[27];

    float* ws = (float*)d_ws;
    size_t off = 0;
    auto alloc = [&](size_t nelem) { float* r = ws + off; off += nelem; return r; };
    p.hidden = alloc((size_t)B * N * H);
    p.nvs    = alloc((size_t)B * N * E);
    p.nvt    = alloc((size_t)B * N * E);
    p.Mcomb  = alloc((size_t)B * N * N);
    p.K1     = alloc((size_t)N * N);
    p.K2     = alloc((size_t)N * N);
    p.comb   = alloc((size_t)B * N * CC);
    p.comb2  = alloc((size_t)B * N * CC);
    p.z      = alloc((size_t)B * N * H);
    p.P1     = alloc((size_t)NPART * B * N * CC);
    p.P2     = alloc((size_t)NPART * B * N * CC);
    p.q      = alloc((size_t)B * N * DA);
    p.kk     = alloc((size_t)B * 4 * N * DA);
    p.th1    = alloc((size_t)B * 4 * N * F);
    p.th2    = alloc((size_t)B * 4 * N * F);
    p.tar32  = alloc((size_t)B * N * TGN_OC);

    float* out = (float*)d_out;
    float* out_gat = out;
    float* out_gru = out + (size_t)B * N * F;
    float* out_fin = out + (size_t)2 * B * N * F;
    float* out_attn = out + (size_t)3 * B * N * F;

    hipMemsetAsync(p.hidden, 0, (size_t)B * N * H * sizeof(float), stream);
    scaleA_kernel<<<N * N / 256, 256, 0, stream>>>(p.A, p.K1);
    k2_kernel<<<dim3(32, 32), 256, 0, stream>>>(p.A, p.K2);

    for (int i = 0; i < 5; ++i) {
        const float* graph = p.sample + (size_t)(4 * i) * N * F;
        gru_step(stream, p, graph, (long)T * N * F);
    }

    qk_kernel<<<(B * N * DA + B * 4 * N * DA) / 256, 256, 0, stream>>>(
        p.sample, p.wq, p.wk, p.attn_bias, p.q, p.kk);
    scores2_kernel<<<dim3(8, 64), 256, 0, stream>>>(p.q, p.kk, p.attn_trans, out_attn);

    const float* srcbase = p.sample + (size_t)(T - 4) * N * F;
    tgn2_kernel<<<dim3(8, 64), 256, 0, stream>>>(
        p.A, out_attn, srcbase, (long)T * N * F, (long)N * F,
        srcbase, (long)T * N * F, (long)N * F, p.th1);
    tgn2_kernel<<<dim3(8, 64), 256, 0, stream>>>(
        p.A, out_attn, p.th1, (long)4 * N * F, (long)N * F,
        srcbase, (long)T * N * F, (long)N * F, p.th2);
    tgn_out_kernel<<<(B * N * TGN_OC) / 256, 256, 0, stream>>>(
        p.sample, p.th1, p.th2, p.Wt, p.bt_, p.tar32);
    gat_kernel<<<(B * N * F) / 256, 256, 0, stream>>>(p.tar32, p.Wsh, p.bsh, out_gat);

    gru_step(stream, p, out_gat, (long)N * F);

    final_kernel<<<(B * N * F) / 256, 256, 0, stream>>>(
        p.hidden, p.tar32, p.Wl, p.bl, p.Wm, p.bm, out_gru, out_fin);
}

// Round 6
// 1524.579 us; speedup vs baseline: 2.7592x; 1.0389x over previous
//
#include <hip/hip_runtime.h>

#define ALPHA_C 0.05f
#define BETA_C  0.95f
#define GAMMA_C 0.95f

constexpr int B = 16, T = 24, N = 512, F = 2, H = 64, E = 16;
constexpr int DA = 8;
constexpr int CC = F + H;    // 66
constexpr int TGN_OC = 32;
constexpr int NPART = 4;     // v-quarter partials

__device__ __forceinline__ float fast_rcp(float x) { return __builtin_amdgcn_rcpf(x); }
__device__ __forceinline__ float fast_tanh(float x) {
    return 1.0f - 2.0f * fast_rcp(__expf(2.0f * x) + 1.0f);
}
__device__ __forceinline__ float fast_sigmoid(float x) {
    return fast_rcp(1.0f + __expf(-x));
}

// K1 = GAMMA*A (one-time)
__global__ void scaleA_kernel(const float* __restrict__ A, float* __restrict__ K1)
{
    int i = blockIdx.x * 256 + threadIdx.x;
    K1[i] = GAMMA_C * A[i];
}

// K2 = GAMMA*ALPHA*A + GAMMA^2 * A@A (one-time). Grid (32,32), 256 thr.
__global__ __launch_bounds__(256) void k2_kernel(const float* __restrict__ A,
                                                 float* __restrict__ K2)
{
    __shared__ float rows[16][258];
    __shared__ float cols[256][17];
    const int tid = threadIdx.x;
    const int r0 = blockIdx.y * 16, c0 = blockIdx.x * 16;
    const int rr = tid >> 4, cc = tid & 15;
    float acc = 0.f;
    for (int k0 = 0; k0 < N; k0 += 256) {
#pragma unroll
        for (int it = 0; it < 4; ++it) {
            int l = it * 256 + tid;
            int row = l >> 6, k4 = (l & 63) << 2;
            *(float4*)&rows[row][k4] = *(const float4*)(A + (size_t)(r0 + row) * N + k0 + k4);
        }
#pragma unroll
        for (int it = 0; it < 4; ++it) {
            int l = it * 256 + tid;
            int k = l >> 2, c4 = (l & 3) << 2;
            *(float4*)&cols[k][c4] = *(const float4*)(A + (size_t)(k0 + k) * N + c0 + c4);
        }
        __syncthreads();
#pragma unroll 8
        for (int k = 0; k < 256; ++k) acc += rows[rr][k] * cols[k][cc];
        __syncthreads();
    }
    size_t i = (size_t)(r0 + rr) * N + c0 + cc;
    K2[i] = GAMMA_C * ALPHA_C * A[i] + GAMMA_C * GAMMA_C * acc;
}

// ---------------------------------------------------------------------------
// bmm core (512 threads): out_part[vq][b,w,c] = (vq==0 ? ALPHA*x : 0)
//                                 + sum_{v in quarter} M[v,w]*in[b,v,c]
// 64x64(+2) tile; thread: cg=tid&15 (4 cols), wg=tid>>4 (2 rows). 8 waves.
// ---------------------------------------------------------------------------
template<int GCOLS, bool INSUM, bool MPB>
__device__ __forceinline__ void bmm_core(
    float* __restrict__ out, const float* __restrict__ x, const float* __restrict__ in,
    const float* __restrict__ M, int b, int w0, int vq, int tid,
    float (*sh_m)[68], float (*sh_h)[68])
{
    constexpr int Crow = 64 + GCOLS;
    const size_t pstr = (size_t)B * N * Crow;
    const int cg = tid & 15;
    const int wg = tid >> 4;    // 0..31

    float acc[2][4] = {{0,0,0,0},{0,0,0,0}};
    float ag[2] = {0.f, 0.f};

    const float* Mb = M + (MPB ? (size_t)b * N * N : 0);
    const float* inb = in + (size_t)b * N * Crow;

    for (int vt = 0; vt < 2; ++vt) {
        const int v0 = vq * 128 + vt * 64;
#pragma unroll
        for (int it = 0; it < 2; ++it) {
            int l = it * 512 + tid;
            int row = l >> 4, c4 = (l & 15) << 2;
            *(float4*)&sh_m[row][c4] =
                *(const float4*)(Mb + (size_t)(v0 + row) * N + w0 + c4);
        }
        if (GCOLS == 2) {
            const float2* h0 = (const float2*)(inb + (size_t)v0 * Crow);
            for (int l = tid; l < 64 * 33; l += 512) {
                int row = l / 33, k = (l - row * 33) * 2;
                float2 v = h0[l];
                if (INSUM) {
#pragma unroll
                    for (int j = 1; j < NPART; ++j) {
                        float2 w = ((const float2*)(inb + (size_t)j * pstr + (size_t)v0 * Crow))[l];
                        v.x += w.x; v.y += w.y;
                    }
                }
                *(float2*)&sh_h[row][k] = v;
            }
        } else {
            const float4* h0 = (const float4*)(inb + (size_t)v0 * Crow);
#pragma unroll
            for (int it = 0; it < 2; ++it) {
                int l = it * 512 + tid;
                int row = l >> 4, k = (l & 15) << 2;
                float4 v = h0[l];
                if (INSUM) {
#pragma unroll
                    for (int j = 1; j < NPART; ++j) {
                        float4 w = ((const float4*)(inb + (size_t)j * pstr + (size_t)v0 * Crow))[l];
                        v.x += w.x; v.y += w.y; v.z += w.z; v.w += w.w;
                    }
                }
                *(float4*)&sh_h[row][k] = v;
            }
        }
        __syncthreads();
#pragma unroll 8
        for (int j = 0; j < 64; ++j) {
            float2 mv = *(const float2*)&sh_m[j][wg << 1];
            float4 hv = *(const float4*)&sh_h[j][cg << 2];
            acc[0][0] += mv.x * hv.x; acc[0][1] += mv.x * hv.y;
            acc[0][2] += mv.x * hv.z; acc[0][3] += mv.x * hv.w;
            acc[1][0] += mv.y * hv.x; acc[1][1] += mv.y * hv.y;
            acc[1][2] += mv.y * hv.z; acc[1][3] += mv.y * hv.w;
            if (GCOLS > 0 && cg < GCOLS) {
                float gv = sh_h[j][64 + cg];
                ag[0] += mv.x * gv; ag[1] += mv.y * gv;
            }
        }
        __syncthreads();
    }
    float* outp = out + (size_t)vq * pstr + (size_t)b * N * Crow;
    const float* xb = x + (size_t)b * N * Crow;
#pragma unroll
    for (int r = 0; r < 2; ++r) {
        const int w = w0 + (wg << 1) + r;
        const size_t base = (size_t)w * Crow + (cg << 2);
        if (GCOLS == 2) {
            float o0 = acc[r][0], o1 = acc[r][1], o2 = acc[r][2], o3 = acc[r][3];
            if (vq == 0) {
                o0 += ALPHA_C * xb[base];     o1 += ALPHA_C * xb[base + 1];
                o2 += ALPHA_C * xb[base + 2]; o3 += ALPHA_C * xb[base + 3];
            }
            float2 lo = {o0, o1}, hi = {o2, o3};
            *(float2*)(outp + base) = lo;
            *(float2*)(outp + base + 2) = hi;
            if (cg < GCOLS) {
                size_t gb = (size_t)w * Crow + 64 + cg;
                float v = ag[r];
                if (vq == 0) v += ALPHA_C * xb[gb];
                outp[gb] = v;
            }
        } else {
            float4 ov = {acc[r][0], acc[r][1], acc[r][2], acc[r][3]};
            if (vq == 0) {
                float4 xv = *(const float4*)(xb + base);
                ov.x += ALPHA_C * xv.x; ov.y += ALPHA_C * xv.y;
                ov.z += ALPHA_C * xv.z; ov.w += ALPHA_C * xv.w;
            }
            *(float4*)(outp + base) = ov;
        }
    }
}

// rnn bmm: grid (8, 4, B), 512 thr
template<bool INSUM>
__global__ __launch_bounds__(512) void bmm4_kernel(
    float* __restrict__ out, const float* __restrict__ x, const float* __restrict__ in,
    const float* __restrict__ M)
{
    __shared__ float sh_m[64][68];
    __shared__ float sh_h[64][68];
    bmm_core<2, INSUM, true>(out, x, in, M, blockIdx.z, blockIdx.x * 64, blockIdx.y,
                             threadIdx.x, sh_m, sh_h);
}

// fused hyper: grid (8, 8, B), 512 thr: y = vq(0..3) | which(0..1)<<2.
__global__ __launch_bounds__(512) void hyper_kernel(
    float* __restrict__ P1, float* __restrict__ P2, const float* __restrict__ hidden,
    const float* __restrict__ K1, const float* __restrict__ K2)
{
    __shared__ float sh_m[64][68];
    __shared__ float sh_h[64][68];
    int vq = blockIdx.y & 3, which = blockIdx.y >> 2;
    float* out = which ? P2 : P1;
    const float* M = which ? K2 : K1;
    bmm_core<0, false, false>(out, hidden, hidden, M, blockIdx.z, blockIdx.x * 64, vq,
                              threadIdx.x, sh_m, sh_h);
}

// ---------------------------------------------------------------------------
// gsgt: 16-row slabs (grid 512), 256 thr: one (row,e) per thread.
// ---------------------------------------------------------------------------
__global__ __launch_bounds__(256) void gsgt4_kernel(
    const float* __restrict__ hidden, const float* __restrict__ P1, const float* __restrict__ P2,
    const float* __restrict__ Wa1, const float* __restrict__ ba1,
    const float* __restrict__ Wa2, const float* __restrict__ ba2,
    const float* __restrict__ graph, long gstride,
    const float* __restrict__ Wsrc, const float* __restrict__ bsrc,
    const float* __restrict__ Wtgt, const float* __restrict__ btgt,
    float* __restrict__ nv_s, float* __restrict__ nv_t)
{
    constexpr size_t psH = (size_t)B * N * H;
    __shared__ float sh[16][194];
    const int tid = threadIdx.x;
    const int e = tid & 15;
    const int row = tid >> 4;
    const size_t nn0 = (size_t)blockIdx.x * 16;
    {
        int f4 = ((int)(nn0) + row) * 16 + e;
        float4 v = ((const float4*)hidden)[f4];
        *(float4*)&sh[row][e << 2] = v;
        float4 a = ((const float4*)P1)[f4];
#pragma unroll
        for (int j = 1; j < NPART; ++j) {
            float4 w = ((const float4*)(P1 + (size_t)j * psH))[f4];
            a.x += w.x; a.y += w.y; a.z += w.z; a.w += w.w;
        }
        *(float4*)&sh[row][64 + (e << 2)] = a;
        float4 c = ((const float4*)P2)[f4];
#pragma unroll
        for (int j = 1; j < NPART; ++j) {
            float4 w = ((const float4*)(P2 + (size_t)j * psH))[f4];
            c.x += w.x; c.y += w.y; c.z += w.z; c.w += w.w;
        }
        *(float4*)&sh[row][128 + (e << 2)] = c;
    }
    __syncthreads();
    float gs = ba1[e], gt = ba2[e];
#pragma unroll 4
    for (int sk = 0; sk < 192; ++sk) {
        float v = sh[row][sk];
        gs += v * Wa1[(size_t)sk * E + e];
        gt += v * Wa2[(size_t)sk * E + e];
    }
    size_t nn = nn0 + row;
    int b = (int)(nn >> 9), n = (int)(nn & (N - 1));
    const float* g = graph + (size_t)b * gstride + (size_t)n * F;
    float g0 = g[0], g1 = g[1];
    float es = g0 * Wsrc[e] + g1 * Wsrc[E + e] + bsrc[e];
    float et = g0 * Wtgt[e] + g1 * Wtgt[E + e] + btgt[e];
    nv_s[nn * E + e] = fast_tanh(2.0f * es * gs);
    nv_t[nn * E + e] = fast_tanh(2.0f * et * gt);
}

// ---------------------------------------------------------------------------
// adp: 4 rows/block, grid (128,16), 512 thr.
// ---------------------------------------------------------------------------
__global__ __launch_bounds__(512) void adp3_kernel(
    const float* __restrict__ nv_s, const float* __restrict__ nv_t,
    const float* __restrict__ A,
    const float* __restrict__ hidden, const float* __restrict__ graph, long gstride,
    float* __restrict__ Mcomb, float* __restrict__ comb)
{
    __shared__ float red[8][4];
    __shared__ float tot[4];
    const int m = threadIdx.x;
    const int n0 = blockIdx.x * 4;
    const int b = blockIdx.y;
    const float4* sm = (const float4*)(nv_s + ((size_t)b * N + m) * E);
    const float4* tm = (const float4*)(nv_t + ((size_t)b * N + m) * E);
    const float4* sn = (const float4*)(nv_s + ((size_t)b * N + n0) * E);
    const float4* tn = (const float4*)(nv_t + ((size_t)b * N + n0) * E);
    float a1[4] = {0.f,0.f,0.f,0.f}, a2[4] = {0.f,0.f,0.f,0.f};
#pragma unroll
    for (int dd = 0; dd < 4; ++dd) {
        float4 smv = sm[dd], tmv = tm[dd];
#pragma unroll
        for (int r = 0; r < 4; ++r) {
            float4 snv = sn[r * 4 + dd], tnv = tn[r * 4 + dd];
            a1[r] += snv.x * tmv.x + snv.y * tmv.y + snv.z * tmv.z + snv.w * tmv.w;
            a2[r] += tnv.x * smv.x + tnv.y * smv.y + tnv.z * smv.z + tnv.w * smv.w;
        }
    }
    float p[4];
#pragma unroll
    for (int r = 0; r < 4; ++r) {
        float pv = fmaxf(fast_tanh(2.0f * (a1[r] - a2[r])), 0.0f);
        if (m == n0 + r) pv += 1.0f;
        p[r] = pv;
    }
    float sr[4] = {p[0], p[1], p[2], p[3]};
    for (int o = 32; o > 0; o >>= 1) {
#pragma unroll
        for (int r = 0; r < 4; ++r) sr[r] += __shfl_down(sr[r], o);
    }
    int wid = m >> 6, lane = m & 63;
    if (lane == 0) {
#pragma unroll
        for (int r = 0; r < 4; ++r) red[wid][r] = sr[r];
    }
    __syncthreads();
    if (m < 4) {
        float t = 0.f;
        for (int i = 0; i < 8; ++i) t += red[i][m];
        tot[m] = BETA_C * fast_rcp(t);
    }
    __syncthreads();
#pragma unroll
    for (int r = 0; r < 4; ++r)
        Mcomb[((size_t)b * N + n0 + r) * N + m] =
            GAMMA_C * A[(size_t)(n0 + r) * N + m] + p[r] * tot[r];
    if (m < 4 * CC) {
        int r = m / CC, k = m - r * CC;
        size_t nn = (size_t)b * N + n0 + r;
        float v;
        if (k < F) v = graph[(size_t)b * gstride + (size_t)(n0 + r) * F + k];
        else       v = hidden[nn * H + (k - F)];
        comb[nn * CC + k] = v;
    }
}

// ---------------------------------------------------------------------------
// zr / cup: 16-row slabs (grid 512), 256 thr, sum 4 partials.
// ---------------------------------------------------------------------------
__device__ __forceinline__ void stage_rnn4(float (*sh)[200], const float* base,
                                           const float* P1, const float* P2,
                                           size_t nn0, int tid)
{
    constexpr size_t psC = (size_t)B * N * CC;
    const float2* c2 = (const float2*)(base + nn0 * CC);
    for (int l = tid; l < 16 * 33; l += 256) {
        int row = l / 33, k = (l - row * 33) * 2;
        *(float2*)&sh[row][k] = c2[l];
        float2 a = ((const float2*)(P1 + nn0 * CC))[l];
#pragma unroll
        for (int j = 1; j < NPART; ++j) {
            float2 w = ((const float2*)(P1 + (size_t)j * psC + nn0 * CC))[l];
            a.x += w.x; a.y += w.y;
        }
        *(float2*)&sh[row][66 + k] = a;
        float2 c = ((const float2*)(P2 + nn0 * CC))[l];
#pragma unroll
        for (int j = 1; j < NPART; ++j) {
            float2 w = ((const float2*)(P2 + (size_t)j * psC + nn0 * CC))[l];
            c.x += w.x; c.y += w.y;
        }
        *(float2*)&sh[row][132 + k] = c;
    }
    __syncthreads();
}

__global__ __launch_bounds__(256) void zr4_kernel(
    const float* __restrict__ comb, const float* __restrict__ P1, const float* __restrict__ P2,
    const float* __restrict__ Wgz, const float* __restrict__ bgz,
    const float* __restrict__ Wgr, const float* __restrict__ bgr,
    const float* __restrict__ hidden,
    float* __restrict__ z, float* __restrict__ comb2)
{
    __shared__ float sh[16][200];
    const int tid = threadIdx.x;
    const int oc = tid & 63;
    const int rg = tid >> 6;
    const size_t nn0 = (size_t)blockIdx.x * 16;
    stage_rnn4(sh, comb, P1, P2, nn0, tid);
    float accz[4], accr[4];
#pragma unroll
    for (int rr = 0; rr < 4; ++rr) { accz[rr] = bgz[oc]; accr[rr] = bgr[oc]; }
#pragma unroll 2
    for (int sk = 0; sk < 198; ++sk) {
        float wz = Wgz[(size_t)sk * H + oc];
        float wr = Wgr[(size_t)sk * H + oc];
#pragma unroll
        for (int rr = 0; rr < 4; ++rr) {
            float v = sh[rg * 4 + rr][sk];
            accz[rr] += v * wz; accr[rr] += v * wr;
        }
    }
#pragma unroll
    for (int rr = 0; rr < 4; ++rr) {
        int row = rg * 4 + rr;
        size_t nn = nn0 + row;
        float zv = fast_sigmoid(accz[rr]);
        float rv = fast_sigmoid(accr[rr]);
        z[nn * H + oc] = zv;
        comb2[nn * CC + F + oc] = rv * hidden[nn * H + oc];
        if (oc < F) comb2[nn * CC + oc] = sh[row][oc];
    }
}

__global__ __launch_bounds__(256) void cup4_kernel(
    const float* __restrict__ comb2, const float* __restrict__ P1, const float* __restrict__ P2,
    const float* __restrict__ Wgc, const float* __restrict__ bgc,
    const float* __restrict__ z, float* __restrict__ hidden)
{
    __shared__ float sh[16][200];
    const int tid = threadIdx.x;
    const int oc = tid & 63;
    const int rg = tid >> 6;
    const size_t nn0 = (size_t)blockIdx.x * 16;
    stage_rnn4(sh, comb2, P1, P2, nn0, tid);
    float acc[4];
#pragma unroll
    for (int rr = 0; rr < 4; ++rr) acc[rr] = bgc[oc];
#pragma unroll 2
    for (int sk = 0; sk < 198; ++sk) {
        float wc = Wgc[(size_t)sk * H + oc];
#pragma unroll
        for (int rr = 0; rr < 4; ++rr) acc[rr] += sh[rg * 4 + rr][sk] * wc;
    }
#pragma unroll
    for (int rr = 0; rr < 4; ++rr) {
        size_t nn = nn0 + rg * 4 + rr;
        float cv = fast_tanh(acc[rr]);
        float zv = z[nn * H + oc];
        float ho = hidden[nn * H + oc];
        hidden[nn * H + oc] = zv * ho + (1.0f - zv) * cv;
    }
}

// q/k precompute
__global__ void qk_kernel(const float* __restrict__ sample,
                          const float* __restrict__ wq, const float* __restrict__ wk,
                          const float* __restrict__ attn_bias,
                          float* __restrict__ q, float* __restrict__ kk)
{
    int idx = blockIdx.x * 256 + threadIdx.x;
    if (idx < B * N * DA) {
        int d = idx & 7;
        int n = (idx >> 3) & (N - 1);
        int b = idx >> 12;
        const float* tar = sample + (((size_t)b * T + (T - 1)) * N + n) * F;
        q[idx] = tar[0] * wq[d] + tar[1] * wq[DA + d] + attn_bias[d];
    } else {
        int j = idx - B * N * DA;
        int d = j & 7;
        int n = (j >> 3) & (N - 1);
        int t = (j >> 12) & 3;
        int b = j >> 14;
        const float* s = sample + (((size_t)b * T + (T - 4 + t)) * N + n) * F;
        kk[j] = s[0] * wk[d] + s[1] * wk[DA + d];
    }
}

// scores v3: grid (32, 64), 256 thr; wave handles 4 rows, lane covers 8 m's.
__global__ __launch_bounds__(256) void scores3_kernel(
    const float* __restrict__ q, const float* __restrict__ kk,
    const float* __restrict__ trans, float* __restrict__ attn)
{
    int bt = blockIdx.y;
    int b = bt >> 2;
    int rbase = blockIdx.x * 16;
    int wid = threadIdx.x >> 6, lane = threadIdx.x & 63;
    const float* kkbt = kk + (size_t)bt * N * DA;
    float* attnbt = attn + (size_t)bt * N * N;
    float tr[8];
#pragma unroll
    for (int d = 0; d < 8; ++d) tr[d] = trans[d];
    for (int i = 0; i < 4; ++i) {
        int n = rbase + wid * 4 + i;
        const float* qp = q + ((size_t)b * N + n) * DA;
        float4 qa = *(const float4*)qp, qb = *(const float4*)(qp + 4);
        float ev[8]; float ssum = 0.f;
#pragma unroll
        for (int k = 0; k < 8; ++k) {
            const float* kp = kkbt + (size_t)(k * 64 + lane) * DA;
            float4 ka = *(const float4*)kp, kb = *(const float4*)(kp + 4);
            float s = fast_tanh(qa.x + ka.x) * tr[0] + fast_tanh(qa.y + ka.y) * tr[1]
                    + fast_tanh(qa.z + ka.z) * tr[2] + fast_tanh(qa.w + ka.w) * tr[3]
                    + fast_tanh(qb.x + kb.x) * tr[4] + fast_tanh(qb.y + kb.y) * tr[5]
                    + fast_tanh(qb.z + kb.z) * tr[6] + fast_tanh(qb.w + kb.w) * tr[7];
            ev[k] = __expf(s);
            ssum += ev[k];
        }
        for (int o = 32; o > 0; o >>= 1) ssum += __shfl_down(ssum, o);
        ssum = __shfl(ssum, 0);
        float rinv = fast_rcp(ssum);
#pragma unroll
        for (int k = 0; k < 8; ++k)
            attnbt[(size_t)n * N + k * 64 + lane] = ev[k] * rinv;
    }
}

// TGN conv: grid (8, 64), 256 thr.
__global__ __launch_bounds__(256) void tgn2_kernel(
    const float* __restrict__ A, const float* __restrict__ attn,
    const float* __restrict__ hbase, long hsB, long hsT,
    const float* __restrict__ xbase, long xsB, long xsT,
    float* __restrict__ out)
{
    __shared__ float sh_m[64][65];
    __shared__ float sh_h[64][2];
    int bt = blockIdx.y;
    int w0 = blockIdx.x * 64;
    int tid = threadIdx.x;
    int wl = tid >> 2, c = tid & 1, vh = (tid >> 1) & 1;
    const float* hp = hbase + (size_t)(bt >> 2) * hsB + (size_t)(bt & 3) * hsT;
    const float* ap = attn + (size_t)bt * N * N;
    float acc = 0.f;
    for (int vt = 0; vt < 8; ++vt) {
        int v0 = vt * 64;
#pragma unroll
        for (int it = 0; it < 16; ++it) {
            int l = it * 256 + tid;
            int vr = l >> 6, wc = l & 63;
            size_t gi = (size_t)(v0 + vr) * N + (w0 + wc);
            sh_m[wc][vr] = A[gi] + ap[gi];
        }
        if (tid < 128) sh_h[tid >> 1][tid & 1] = hp[(size_t)(v0 + (tid >> 1)) * F + (tid & 1)];
        __syncthreads();
#pragma unroll
        for (int jj = 0; jj < 32; ++jj) {
            int j = vh * 32 + jj;
            acc += sh_m[wl][j] * sh_h[j][c];
        }
        __syncthreads();
    }
    acc += __shfl_xor(acc, 2);
    if (vh == 0) {
        const float* xp = xbase + (size_t)(bt >> 2) * xsB + (size_t)(bt & 3) * xsT;
        out[((size_t)bt * N + w0 + wl) * F + c] =
            ALPHA_C * xp[(size_t)(w0 + wl) * F + c] + GAMMA_C * acc;
    }
}

// tgn_out + gat fused: block = 8 rows x 32 oc, grid B*N/8.
__global__ __launch_bounds__(256) void tgn_out_gat_kernel(
    const float* __restrict__ sample,
    const float* __restrict__ th1, const float* __restrict__ th2,
    const float* __restrict__ Wt, const float* __restrict__ bt_,
    const float* __restrict__ Ws, const float* __restrict__ bs,
    float* __restrict__ tar32, float* __restrict__ out0)
{
    __shared__ float sh_t[8][33];
    const int tid = threadIdx.x;
    const int oc = tid & 31;
    const int r = tid >> 5;
    const size_t nn = (size_t)blockIdx.x * 8 + r;
    const int n = (int)(nn & (N - 1));
    const int b = (int)(nn >> 9);
    float acc = 0.f;
    for (int t = 0; t < 4; ++t) {
        int bt = b * 4 + t;
        const float* s = sample + (((size_t)b * T + (T - 4 + t)) * N + n) * F;
        size_t rr = ((size_t)bt * N + n) * F;
        float v = bt_[oc];
        v += s[0] * Wt[0 * TGN_OC + oc] + s[1] * Wt[1 * TGN_OC + oc];
        v += th1[rr] * Wt[2 * TGN_OC + oc] + th1[rr + 1] * Wt[3 * TGN_OC + oc];
        v += th2[rr] * Wt[4 * TGN_OC + oc] + th2[rr + 1] * Wt[5 * TGN_OC + oc];
        acc += fmaxf(v, 0.0f);
    }
    tar32[nn * TGN_OC + oc] = acc;
    sh_t[r][oc] = acc;
    __syncthreads();
    if (tid < 16) {
        int row = tid >> 1, f = tid & 1;
        size_t nn2 = (size_t)blockIdx.x * 8 + row;
        float g = bs[f];
#pragma unroll
        for (int k = 0; k < TGN_OC; ++k) g += sh_t[row][k] * Ws[(size_t)k * F + f];
        out0[nn2 * F + f] = g;
    }
}

__global__ void final_kernel(const float* __restrict__ hidden, const float* __restrict__ tar32,
                             const float* __restrict__ Wl, const float* __restrict__ bl,
                             const float* __restrict__ Wm, const float* __restrict__ bm,
                             float* __restrict__ dout_gru, float* __restrict__ dout_fin)
{
    int idx = blockIdx.x * 256 + threadIdx.x;
    int f = idx & 1;
    int nn = idx >> 1;
    const float* hp = hidden + (size_t)nn * H;
    const float* tp = tar32 + (size_t)nn * TGN_OC;
    float g = bl[f], fin = bm[f];
    for (int k = 0; k < H; ++k) g += hp[k] * Wl[(size_t)k * F + f];
    for (int k = 0; k < TGN_OC; ++k) fin += tp[k] * Wm[(size_t)k * F + f];
    for (int k = 0; k < H; ++k) fin += hp[k] * Wm[(size_t)(TGN_OC + k) * F + f];
    dout_gru[idx] = g;
    dout_fin[idx] = fin;
}

// ---------------------------------------------------------------------------
// Host side
// ---------------------------------------------------------------------------
namespace {
struct Ptrs {
    const float *sample, *A, *wq, *wk, *attn_bias, *attn_trans, *Wt, *bt_;
    const float *Wa1, *ba1, *Wa2, *ba2, *Wsrc, *bsrc, *Wtgt, *btgt;
    const float *Wgz, *bgz, *Wgr, *bgr, *Wgc, *bgc, *Wsh, *bsh, *Wl, *bl, *Wm, *bm;
    float *hidden, *nvs, *nvt, *Mcomb, *K1, *K2, *comb, *comb2, *z, *P1, *P2;
    float *q, *kk, *th1, *th2, *tar32;
};

void gru_step(hipStream_t stream, const Ptrs& p, const float* graph, long gstride)
{
    dim3 bg(8, NPART, B);   // 512 blocks x 8 waves
    hyper_kernel<<<dim3(8, 2 * NPART, B), 512, 0, stream>>>(p.P1, p.P2, p.hidden, p.K1, p.K2);
    gsgt4_kernel<<<B * N / 16, 256, 0, stream>>>(
        p.hidden, p.P1, p.P2, p.Wa1, p.ba1, p.Wa2, p.ba2, graph, gstride,
        p.Wsrc, p.bsrc, p.Wtgt, p.btgt, p.nvs, p.nvt);
    adp3_kernel<<<dim3(N / 4, B), 512, 0, stream>>>(
        p.nvs, p.nvt, p.A, p.hidden, graph, gstride, p.Mcomb, p.comb);
    bmm4_kernel<false><<<bg, 512, 0, stream>>>(p.P1, p.comb, p.comb, p.Mcomb);
    bmm4_kernel<true><<<bg, 512, 0, stream>>>(p.P2, p.comb, p.P1, p.Mcomb);
    zr4_kernel<<<B * N / 16, 256, 0, stream>>>(
        p.comb, p.P1, p.P2, p.Wgz, p.bgz, p.Wgr, p.bgr, p.hidden, p.z, p.comb2);
    bmm4_kernel<false><<<bg, 512, 0, stream>>>(p.P1, p.comb2, p.comb2, p.Mcomb);
    bmm4_kernel<true><<<bg, 512, 0, stream>>>(p.P2, p.comb2, p.P1, p.Mcomb);
    cup4_kernel<<<B * N / 16, 256, 0, stream>>>(
        p.comb2, p.P1, p.P2, p.Wgc, p.bgc, p.z, p.hidden);
}
}  // namespace

extern "C" void kernel_launch(void* const* d_in, const int* in_sizes, int n_in,
                              void* d_out, int out_size, void* d_ws, size_t ws_size,
                              hipStream_t stream)
{
    (void)in_sizes; (void)n_in; (void)out_size; (void)ws_size;
    Ptrs p;
    p.sample = (const float*)d_in[0];
    p.A      = (const float*)d_in[1];
    p.wq     = (const float*)d_in[2];
    p.wk     = (const float*)d_in[3];
    p.attn_bias  = (const float*)d_in[4];
    p.attn_trans = (const float*)d_in[5];
    p.Wt  = (const float*)d_in[6];
    p.bt_ = (const float*)d_in[7];
    p.Wa1 = (const float*)d_in[8];
    p.ba1 = (const float*)d_in[9];
    p.Wa2 = (const float*)d_in[10];
    p.ba2 = (const float*)d_in[11];
    p.Wsrc = (const float*)d_in[12];
    p.bsrc = (const float*)d_in[13];
    p.Wtgt = (const float*)d_in[14];
    p.btgt = (const float*)d_in[15];
    p.Wgz = (const float*)d_in[16];
    p.bgz = (const float*)d_in[17];
    p.Wgr = (const float*)d_in[18];
    p.bgr = (const float*)d_in[19];
    p.Wgc = (const float*)d_in[20];
    p.bgc = (const float*)d_in[21];
    p.Wsh = (const float*)d_in[22];
    p.bsh = (const float*)d_in[23];
    p.Wl  = (const float*)d_in[24];
    p.bl  = (const float*)d_in[25];
    p.Wm  = (const float*)d_in[26];
    p.bm  = (const float*)d_in[27];

    float* ws = (float*)d_ws;
    size_t off = 0;
    auto alloc = [&](size_t nelem) { float* r = ws + off; off += nelem; return r; };
    p.hidden = alloc((size_t)B * N * H);
    p.nvs    = alloc((size_t)B * N * E);
    p.nvt    = alloc((size_t)B * N * E);
    p.Mcomb  = alloc((size_t)B * N * N);
    p.K1     = alloc((size_t)N * N);
    p.K2     = alloc((size_t)N * N);
    p.comb   = alloc((size_t)B * N * CC);
    p.comb2  = alloc((size_t)B * N * CC);
    p.z      = alloc((size_t)B * N * H);
    p.P1     = alloc((size_t)NPART * B * N * CC);
    p.P2     = alloc((size_t)NPART * B * N * CC);
    p.q      = alloc((size_t)B * N * DA);
    p.kk     = alloc((size_t)B * 4 * N * DA);
    p.th1    = alloc((size_t)B * 4 * N * F);
    p.th2    = alloc((size_t)B * 4 * N * F);
    p.tar32  = alloc((size_t)B * N * TGN_OC);

    float* out = (float*)d_out;
    float* out_gat = out;
    float* out_gru = out + (size_t)B * N * F;
    float* out_fin = out + (size_t)2 * B * N * F;
    float* out_attn = out + (size_t)3 * B * N * F;

    hipMemsetAsync(p.hidden, 0, (size_t)B * N * H * sizeof(float), stream);
    scaleA_kernel<<<N * N / 256, 256, 0, stream>>>(p.A, p.K1);
    k2_kernel<<<dim3(32, 32), 256, 0, stream>>>(p.A, p.K2);

    for (int i = 0; i < 5; ++i) {
        const float* graph = p.sample + (size_t)(4 * i) * N * F;
        gru_step(stream, p, graph, (long)T * N * F);
    }

    qk_kernel<<<(B * N * DA + B * 4 * N * DA) / 256, 256, 0, stream>>>(
        p.sample, p.wq, p.wk, p.attn_bias, p.q, p.kk);
    scores3_kernel<<<dim3(32, 64), 256, 0, stream>>>(p.q, p.kk, p.attn_trans, out_attn);

    const float* srcbase = p.sample + (size_t)(T - 4) * N * F;
    tgn2_kernel<<<dim3(8, 64), 256, 0, stream>>>(
        p.A, out_attn, srcbase, (long)T * N * F, (long)N * F,
        srcbase, (long)T * N * F, (long)N * F, p.th1);
    tgn2_kernel<<<dim3(8, 64), 256, 0, stream>>>(
        p.A, out_attn, p.th1, (long)4 * N * F, (long)N * F,
        srcbase, (long)T * N * F, (long)N * F, p.th2);
    tgn_out_gat_kernel<<<B * N / 8, 256, 0, stream>>>(
        p.sample, p.th1, p.th2, p.Wt, p.bt_, p.Wsh, p.bsh, p.tar32, out_gat);

    gru_step(stream, p, out_gat, (long)N * F);

    final_kernel<<<(B * N * F) / 256, 256, 0, stream>>>(
        p.hidden, p.tar32, p.Wl, p.bl, p.Wm, p.bm, out_gru, out_fin);
}